// Round 1
// baseline (402.783 us; speedup 1.0000x reference)
//
#include <hip/hip_runtime.h>
#include <math.h>

#define N_NODES 50000
#define N_EDGES 800000
#define D_FEAT 64

// Order-preserving float->uint map so we can use integer atomicMax for
// a float segment-max (robust for any sign of beta*ea).
__device__ __forceinline__ unsigned enc_f(float f) {
    unsigned u = __float_as_uint(f);
    return (u & 0x80000000u) ? ~u : (u | 0x80000000u);
}
__device__ __forceinline__ float dec_f(unsigned u) {
    return __uint_as_float((u & 0x80000000u) ? (u & 0x7fffffffu) : ~u);
}

// 1) sq[r] = sum of edge_attr^2 over edges with row==r
__global__ void k_sq(const float* __restrict__ w, const int* __restrict__ row,
                     float* __restrict__ sq) {
    int e = blockIdx.x * blockDim.x + threadIdx.x;
    if (e < N_EDGES) {
        float v = w[e];
        atomicAdd(&sq[row[e]], v * v);
    }
}

// 2) xn = row-wise L2 normalized x; also init amax_enc[i] = enc(beta*1) (self-loop)
__global__ void k_node_norm(const float* __restrict__ x, float* __restrict__ xn,
                            unsigned* __restrict__ amax_enc,
                            const float* __restrict__ beta) {
    int i = blockIdx.x * 4 + (threadIdx.x >> 6);
    int lane = threadIdx.x & 63;
    if (i >= N_NODES) return;
    float v = x[i * D_FEAT + lane];
    float s = v * v;
    #pragma unroll
    for (int off = 32; off; off >>= 1) s += __shfl_xor(s, off, 64);
    float inv = 1.0f / fmaxf(sqrtf(s), 1e-12f);
    xn[i * D_FEAT + lane] = v * inv;
    if (lane == 0) amax_enc[i] = enc_f(beta[0]);
}

// 3) segment max of alpha = beta * (w / max(sqrt(sq[row]),eps))
__global__ void k_amax(const float* __restrict__ w, const int* __restrict__ row,
                       const float* __restrict__ sq, unsigned* __restrict__ amax_enc,
                       const float* __restrict__ beta) {
    int e = blockIdx.x * blockDim.x + threadIdx.x;
    if (e < N_EDGES) {
        int r = row[e];
        float ea = w[e] / fmaxf(sqrtf(sq[r]), 1e-12f);
        float alpha = beta[0] * ea;
        atomicMax(&amax_enc[r], enc_f(alpha));
    }
}

// 4) ex[e] = exp(alpha - amax[row]); denom[row] += ex
__global__ void k_ex(const float* __restrict__ w, const int* __restrict__ row,
                     const float* __restrict__ sq, const unsigned* __restrict__ amax_enc,
                     float* __restrict__ ex, float* __restrict__ denom,
                     const float* __restrict__ beta) {
    int e = blockIdx.x * blockDim.x + threadIdx.x;
    if (e < N_EDGES) {
        int r = row[e];
        float ea = w[e] / fmaxf(sqrtf(sq[r]), 1e-12f);
        float alpha = beta[0] * ea;
        float v = expf(alpha - dec_f(amax_enc[r]));
        ex[e] = v;
        atomicAdd(&denom[r], v);
    }
}

// 5) add the self-loop exp term into denom
__global__ void k_selfdenom(const unsigned* __restrict__ amax_enc,
                            float* __restrict__ denom, const float* __restrict__ beta) {
    int i = blockIdx.x * blockDim.x + threadIdx.x;
    if (i < N_NODES) {
        denom[i] += expf(beta[0] - dec_f(amax_enc[i]));
    }
}

// 6) scatter SpMM: out[row_e, :] += a_e * xn[col_e, :], one wave per edge
__global__ void k_scatter(const int* __restrict__ row, const int* __restrict__ col,
                          const float* __restrict__ ex, const float* __restrict__ denom,
                          const float* __restrict__ xn, float* __restrict__ out) {
    int idx = blockIdx.x * 256 + threadIdx.x;
    int e = idx >> 6;
    int lane = idx & 63;
    if (e >= N_EDGES) return;
    int r = row[e];
    int c = col[e];
    float a = ex[e] / (denom[r] + 1e-16f);
    atomicAdd(&out[r * D_FEAT + lane], a * xn[c * D_FEAT + lane]);
}

// 7) out += (1 + eps + a_self) * xn
__global__ void k_final(const float* __restrict__ xn, const unsigned* __restrict__ amax_enc,
                        const float* __restrict__ denom, const float* __restrict__ beta,
                        const float* __restrict__ epsp, float* __restrict__ out) {
    int idx = blockIdx.x * blockDim.x + threadIdx.x;
    if (idx >= N_NODES * D_FEAT) return;
    int i = idx >> 6;
    float a_self = expf(beta[0] - dec_f(amax_enc[i])) / (denom[i] + 1e-16f);
    out[idx] += (1.0f + epsp[0] + a_self) * xn[idx];
}

extern "C" void kernel_launch(void* const* d_in, const int* in_sizes, int n_in,
                              void* d_out, int out_size, void* d_ws, size_t ws_size,
                              hipStream_t stream) {
    const float* x         = (const float*)d_in[0];
    const float* edge_attr = (const float*)d_in[1];
    const float* beta      = (const float*)d_in[2];
    const float* eps       = (const float*)d_in[3];
    const int*   ei        = (const int*)d_in[4];
    const int*   row = ei;
    const int*   col = ei + N_EDGES;
    float* out = (float*)d_out;

    // workspace layout (floats): sq[N] | amax_enc[N] | denom[N] | ex[E] | xn[N*64]
    float*    ws       = (float*)d_ws;
    float*    sq       = ws;
    unsigned* amax_enc = (unsigned*)(ws + N_NODES);
    float*    denom    = ws + 2 * N_NODES;
    float*    ex       = ws + 3 * N_NODES;
    float*    xn       = ws + 3 * N_NODES + N_EDGES;

    hipMemsetAsync(sq, 0, N_NODES * sizeof(float), stream);
    hipMemsetAsync(denom, 0, N_NODES * sizeof(float), stream);
    hipMemsetAsync(out, 0, N_NODES * D_FEAT * sizeof(float), stream);

    const int TB = 256;
    k_sq<<<(N_EDGES + TB - 1) / TB, TB, 0, stream>>>(edge_attr, row, sq);
    k_node_norm<<<(N_NODES + 3) / 4, TB, 0, stream>>>(x, xn, amax_enc, beta);
    k_amax<<<(N_EDGES + TB - 1) / TB, TB, 0, stream>>>(edge_attr, row, sq, amax_enc, beta);
    k_ex<<<(N_EDGES + TB - 1) / TB, TB, 0, stream>>>(edge_attr, row, sq, amax_enc, ex, denom, beta);
    k_selfdenom<<<(N_NODES + TB - 1) / TB, TB, 0, stream>>>(amax_enc, denom, beta);
    k_scatter<<<(N_EDGES * 64 + TB - 1) / TB, TB, 0, stream>>>(row, col, ex, denom, xn, out);
    k_final<<<(N_NODES * D_FEAT + TB - 1) / TB, TB, 0, stream>>>(xn, amax_enc, denom, beta, eps, out);
}